// Round 1
// 492.266 us; speedup vs baseline: 1.0503x; 1.0503x over previous
//
#include <hip/hip_runtime.h>

// B=4, S=2048 -> M=8192 rows; OUT_F=N=4096; IN_F=K=4096; GROUP=128.
#define K_DIM 4096
#define N_DIM 4096
#define M_DIM 8192
#define NT 64  // K-tiles of BK=64

typedef __bf16 bf16;
typedef __attribute__((ext_vector_type(8))) __bf16 bf16x8;
typedef __attribute__((ext_vector_type(4))) float f32x4;
typedef __attribute__((ext_vector_type(8))) unsigned short u16x8;

// fp32 -> bf16 round-to-nearest-even
__device__ inline unsigned short f2bf(float f) {
    unsigned u = __builtin_bit_cast(unsigned, f);
    u += 0x7fffu + ((u >> 16) & 1u);
    return (unsigned short)(u >> 16);
}

// ---- fused prep, grid-stride (2048 blocks): x->bf16; W[n,k]=bf16(sign*scale) ----
// 524288 threads; 8 x-granules + 4 W-granules (16B each) per thread, exact fit.
__global__ __launch_bounds__(256) void prep_kernel(const float* __restrict__ x,
                                                   const float* __restrict__ sw,
                                                   const float* __restrict__ scales,
                                                   unsigned short* __restrict__ oA,
                                                   unsigned short* __restrict__ oW) {
    const unsigned T = blockIdx.x * 256u + threadIdx.x;
#pragma unroll
    for (int k = 0; k < 8; ++k) {  // 8*524288 = 4194304 = (8192*4096)/8
        const size_t i = (size_t)k * 524288u + T;
        const float4* p = (const float4*)x + i * 2;
        const float4 a = p[0], c = p[1];
        u16x8 v;
        v[0] = f2bf(a.x); v[1] = f2bf(a.y); v[2] = f2bf(a.z); v[3] = f2bf(a.w);
        v[4] = f2bf(c.x); v[5] = f2bf(c.y); v[6] = f2bf(c.z); v[7] = f2bf(c.w);
        *((u16x8*)oA + i) = v;
    }
#pragma unroll
    for (int k = 0; k < 4; ++k) {  // 4*524288 = 2097152 = (4096*4096)/8
        const size_t i = (size_t)k * 524288u + T;
        const float s = scales[i >> 4];  // 8 elems/granule, 128/group -> i/16
        const float4* p = (const float4*)sw + i * 2;
        const float4 a = p[0], c = p[1];
        u16x8 v;
        v[0] = f2bf(a.x * s); v[1] = f2bf(a.y * s); v[2] = f2bf(a.z * s); v[3] = f2bf(a.w * s);
        v[4] = f2bf(c.x * s); v[5] = f2bf(c.y * s); v[6] = f2bf(c.z * s); v[7] = f2bf(c.w * s);
        *((u16x8*)oW + i) = v;
    }
}

__device__ inline void gll16(const bf16* g, bf16* l) {
    __builtin_amdgcn_global_load_lds(
        (const __attribute__((address_space(1))) void*)g,
        (__attribute__((address_space(3))) void*)l, 16, 0, 0);
}

// ---- 256x256x64 8-phase GEMM (T2+T3+T4+T5), C[m,n] = sum_k A[m,k]*W[n,k] ----
// 512 thr = 8 waves (2M x 4N), wave tile 128x64, mfma 16x16x32, acc 8x4 f32x4.
// LDS 128 KiB: [buf:2][op A/B][khalf:2][row:256][32 bf16]; region = 16 KiB.
// Swizzle: stored 16B-block sb = logical ^ ((row>>1)&3) -> frag reads 2-way
// (free, m136); staging keeps LDS dest linear, swizzle applied to global src.
// Schedule per K-tile group (4 phases, each: ds_read | 1 half-tile prefetch |
// bar | lgkm0 | 16 MFMA | bar). Region free-times: A-kh0 after p1, B-kh0 p2,
// A-kh1 p3, B-kh1 p4 -> issue {p1: B-kh1(g+1)} {p2/3/4: A0/B0/A1(g+2)}.
// One vmcnt(6) per group (3 half-tiles in flight) -- never drains in main loop.
extern __shared__ bf16 lds[];

__global__ __launch_bounds__(512, 2) void gemm_bt_kernel(const bf16* __restrict__ A,
                                                         const bf16* __restrict__ W,
                                                         float* __restrict__ C) {
    // XCD-aware swizzle (512 blocks, 512%8==0 -> bijective)
    const int raw = blockIdx.x;
    const int swz = (raw & 7) * 64 + (raw >> 3);
    const int m0 = (swz >> 4) * 256;
    const int n0 = (swz & 15) * 256;

    const int t = threadIdx.x;
    const int lane = t & 63;
    const int w = t >> 6;
    const int wm = w >> 2;  // 0..1
    const int wn = w & 3;   // 0..3

    // Staging: granule s = j*512+t -> row s>>2, stored blk s&3,
    // logical blk = (s&3)^((s>>3)&3); identical for j=0,1 (j*128 rows, j*64 s>>3).
    const int srow = t >> 2;
    const int slb = ((t & 3) ^ ((t >> 3) & 3)) * 8;
    const bf16* gA = A + (size_t)(m0 + srow) * K_DIM + slb;
    const bf16* gB = W + (size_t)(n0 + srow) * K_DIM + slb;
    bf16* lA = lds + t * 8;           // + destbuf*32768 + kh*8192
    bf16* lB = lds + 16384 + t * 8;

    // Fragment reads: row = base + (lane&15); (row>>1)&3 == (lane>>1)&3 since
    // all bases are multiples of 16 -> per-lane-constant swizzle offset.
    const int r = lane & 15;
    const int be8 = ((lane >> 4) ^ ((lane >> 1) & 3)) * 8;  // 0/8/16/24 elems
    const bf16* fA = lds + (wm * 128 + r) * 32 + be8;           // + buf*32768 + kh*8192 + mi*512
    const bf16* fB = lds + 16384 + (wn * 64 + r) * 32 + be8;    // + buf*32768 + kh*8192 + ni*512

    f32x4 acc[8][4] = {};
    bf16x8 af[8], b0, b1;

#define STAGE(gbase, kofs, ldst)                                       \
    do {                                                               \
        gll16((gbase) + (kofs), (ldst));                               \
        gll16((gbase) + (size_t)128 * K_DIM + (kofs), (ldst) + 4096);  \
    } while (0)

#define BAR __builtin_amdgcn_s_barrier()
#define LGKM0                                                   \
    do {                                                        \
        asm volatile("s_waitcnt lgkmcnt(0)" ::: "memory");      \
        __builtin_amdgcn_sched_barrier(0);                      \
    } while (0)

#define MFMA_HALF(NIB)                                                               \
    do {                                                                             \
        _Pragma("unroll") for (int mi = 0; mi < 8; ++mi) {                           \
            acc[mi][NIB] = __builtin_amdgcn_mfma_f32_16x16x32_bf16(                  \
                af[mi], b0, acc[mi][NIB], 0, 0, 0);                                  \
            acc[mi][(NIB) + 1] = __builtin_amdgcn_mfma_f32_16x16x32_bf16(            \
                af[mi], b1, acc[mi][(NIB) + 1], 0, 0, 0);                            \
        }                                                                            \
    } while (0)

#define GROUP(BUF, I1, I2, VMC6, VMC0)                                               \
    do {                                                                             \
        /* phase 1: kh0, ni 0-1 */                                                   \
        _Pragma("unroll") for (int mi = 0; mi < 8; ++mi)                             \
            af[mi] = *(const bf16x8*)(fA + (BUF)*32768 + mi * 512);                  \
        b0 = *(const bf16x8*)(fB + (BUF)*32768 + 0 * 512);                           \
        b1 = *(const bf16x8*)(fB + (BUF)*32768 + 1 * 512);                           \
        if (I1) STAGE(gB, ko1, lB + (1 - (BUF)) * 32768 + 8192);                     \
        BAR; LGKM0;                                                                  \
        __builtin_amdgcn_s_setprio(1); MFMA_HALF(0); __builtin_amdgcn_s_setprio(0);  \
        BAR;                                                                         \
        /* phase 2: kh0, ni 2-3 */                                                   \
        b0 = *(const bf16x8*)(fB + (BUF)*32768 + 2 * 512);                           \
        b1 = *(const bf16x8*)(fB + (BUF)*32768 + 3 * 512);                           \
        if (I2) STAGE(gA, ko2, lA + (BUF)*32768);                                    \
        BAR; LGKM0;                                                                  \
        __builtin_amdgcn_s_setprio(1); MFMA_HALF(2); __builtin_amdgcn_s_setprio(0);  \
        BAR;                                                                         \
        /* phase 3: kh1, ni 0-1 */                                                   \
        _Pragma("unroll") for (int mi = 0; mi < 8; ++mi)                             \
            af[mi] = *(const bf16x8*)(fA + (BUF)*32768 + 8192 + mi * 512);           \
        b0 = *(const bf16x8*)(fB + (BUF)*32768 + 8192 + 0 * 512);                    \
        b1 = *(const bf16x8*)(fB + (BUF)*32768 + 8192 + 1 * 512);                    \
        if (I2) STAGE(gB, ko2, lB + (BUF)*32768);                                    \
        BAR; LGKM0;                                                                  \
        __builtin_amdgcn_s_setprio(1); MFMA_HALF(0); __builtin_amdgcn_s_setprio(0);  \
        BAR;                                                                         \
        /* phase 4: kh1, ni 2-3 */                                                   \
        b0 = *(const bf16x8*)(fB + (BUF)*32768 + 8192 + 2 * 512);                    \
        b1 = *(const bf16x8*)(fB + (BUF)*32768 + 8192 + 3 * 512);                    \
        if (I2) STAGE(gA, ko2 + 32, lA + (BUF)*32768 + 8192);                        \
        BAR; LGKM0;                                                                  \
        __builtin_amdgcn_s_setprio(1); MFMA_HALF(2); __builtin_amdgcn_s_setprio(0);  \
        if (VMC6) asm volatile("s_waitcnt vmcnt(6)" ::: "memory");                   \
        if (VMC0) asm volatile("s_waitcnt vmcnt(0)" ::: "memory");                   \
        BAR;                                                                         \
    } while (0)

    // Prologue: tile 0 (4 half-tiles) + tile 1 (3) = 7 issued; wait all but 3.
    STAGE(gA, 0, lA);               // H(0,A,kh0) -> buf0
    STAGE(gB, 0, lB);               // H(0,B,kh0)
    STAGE(gA, 32, lA + 8192);       // H(0,A,kh1)
    STAGE(gB, 32, lB + 8192);       // H(0,B,kh1)
    STAGE(gA, 64, lA + 32768);      // H(1,A,kh0) -> buf1
    STAGE(gB, 64, lB + 32768);      // H(1,B,kh0)
    STAGE(gA, 96, lA + 32768 + 8192);  // H(1,A,kh1)
    asm volatile("s_waitcnt vmcnt(6)" ::: "memory");
    BAR;

    int ko1 = 96;   // group g: B-kh1(g+1) at (g+1)*64+32
    int ko2 = 128;  // group g: tile g+2 at (g+2)*64
#pragma unroll 1
    for (int gg = 0; gg < 31; ++gg) {  // groups 0..61 (steady state)
        GROUP(0, true, true, true, false);
        ko1 += 64; ko2 += 64;
        GROUP(1, true, true, true, false);
        ko1 += 64; ko2 += 64;
    }
    GROUP(0, true, false, false, true);    // g=62: issue B-kh1(63); drain
    GROUP(1, false, false, false, false);  // g=63: compute only

    // Epilogue: 16x16 C/D layout col=lane&15, row=(lane>>4)*4+reg [m89-verified]
    const int cr = lane >> 4;
    float* Cb = C + (size_t)(m0 + wm * 128 + cr * 4) * N_DIM + (n0 + wn * 64 + r);
#pragma unroll
    for (int mi = 0; mi < 8; ++mi)
#pragma unroll
        for (int ni = 0; ni < 4; ++ni)
#pragma unroll
            for (int q = 0; q < 4; ++q)
                Cb[(size_t)(mi * 16 + q) * N_DIM + ni * 16] = acc[mi][ni][q];
}

extern "C" void kernel_launch(void* const* d_in, const int* in_sizes, int n_in,
                              void* d_out, int out_size, void* d_ws, size_t ws_size,
                              hipStream_t stream) {
    const float* x = (const float*)d_in[0];
    const float* sw = (const float*)d_in[1];
    const float* scales = (const float*)d_in[2];
    float* out = (float*)d_out;

    bf16* Abf = (bf16*)d_ws;                                       // 64 MB
    bf16* Wbf = (bf16*)((char*)d_ws + (size_t)M_DIM * K_DIM * 2);  // +32 MB

    static int lds_set = 0;
    if (!lds_set) {
        hipFuncSetAttribute((const void*)gemm_bt_kernel,
                            hipFuncAttributeMaxDynamicSharedMemorySize, 131072);
        lds_set = 1;
    }

    prep_kernel<<<2048, 256, 0, stream>>>(x, sw, scales,
                                          (unsigned short*)Abf, (unsigned short*)Wbf);

    gemm_bt_kernel<<<dim3(N_DIM / 256 * (M_DIM / 256)), 512, 131072, stream>>>(Abf, Wbf, out);
}